// Round 12
// baseline (292.160 us; speedup 1.0000x reference)
//
#include <hip/hip_runtime.h>
#include <hip/hip_cooperative_groups.h>

namespace cg = cooperative_groups;

#define N_NODES 50000
#define N_EDGES 100000
#define NUM_RELS 200
#define DIM 64
#define CAP 512
#define TILES 8
#define KPAD 72            // padded K-stride (ushorts); 144B rows, 16B aligned
#define GB 768             // cooperative grid: 3 blocks/CU — margin vs co-residency limit

typedef __attribute__((ext_vector_type(8))) short bf16x8;
typedef __attribute__((ext_vector_type(8))) unsigned short u16x8;
typedef __attribute__((ext_vector_type(4))) float f32x4;

// ---- workspace layout ----
#define OFF_LAST 0
#define OFF_CUR  50000
#define OFF_BN   50200
#define OFF_BS   152600          // 50200 + 200*512
#define HB_OFF   1020032u        // bf16 h: 50000*64 ushorts
#define WT_OFF   7420032u        // bf16 W^T (K-major): 201*64*64 ushorts (wself = idx 200)

// P1 task split
#define T_WT 201
#define T_EM 391                 // ceil(100000/256)
#define T_HC 391                 // 8192 floats per task
#define P1_TASKS (T_WT + T_EM + T_HC)

// P2 task split
#define T_BK 196                 // ceil(50000/256) bucket chunks
#define NODE_TILES 782           // self tiles
#define P2_TASKS (T_BK + NODE_TILES)

#define MSG_TASKS (NUM_RELS * TILES)   // 1600

__device__ __forceinline__ unsigned short f2bf(float x) {
    union { float f; unsigned u; } v; v.f = x;
    unsigned r = v.u + 0x7FFFu + ((v.u >> 16) & 1u);   // RNE
    return (unsigned short)(r >> 16);
}

__global__ __launch_bounds__(256, 4) void fused_kernel(
    const float* __restrict__ h, const int* __restrict__ edges,
    const float* __restrict__ weight, const float* __restrict__ wself,
    int* __restrict__ ws, unsigned short* __restrict__ hb,
    unsigned short* __restrict__ wt, float* __restrict__ out)
{
    __shared__ __align__(16) char smem[2 * DIM * KPAD * 2];   // 18432 B
    cg::grid_group grid = cg::this_grid();
    const int bid = blockIdx.x, t = threadIdx.x;

    // ---- P0: init last=-1, cur=0 ----
    for (int i = bid * 256 + t; i < N_NODES + NUM_RELS; i += GB * 256) {
        if (i < N_NODES) ws[OFF_LAST + i] = -1;
        else             ws[OFF_CUR + i - N_NODES] = 0;
    }
    grid.sync();

    // ---- P1: W transpose/convert + edge_max + h convert ----
    for (int task = bid; task < P1_TASKS; task += GB) {
        if (task < T_WT) {
            float* Wl = (float*)smem;
            const float* src = (task < NUM_RELS) ? weight + (size_t)task * DIM * DIM : wself;
            __syncthreads();
#pragma unroll
            for (int j = 0; j < 16; ++j) Wl[t + j * 256] = src[t + j * 256];
            __syncthreads();
            int cc = t >> 2, q = t & 3;
            unsigned short tmp[16];
#pragma unroll
            for (int kk = 0; kk < 16; ++kk) tmp[kk] = f2bf(Wl[(q * 16 + kk) * DIM + cc]);
            unsigned short* dst = wt + (size_t)task * DIM * DIM + cc * DIM + q * 16;
            *(u16x8*)dst       = *(const u16x8*)&tmp[0];
            *(u16x8*)(dst + 8) = *(const u16x8*)&tmp[8];
        } else if (task < T_WT + T_EM) {
            int e = (task - T_WT) * 256 + t;
            if (e < N_EDGES) atomicMax(&ws[OFF_LAST + edges[e * 3 + 2]], e);
        } else {
            long off = (long)(task - T_WT - T_EM) * 8192 + (long)t * 32;
            if (off < (long)N_NODES * DIM) {
#pragma unroll
                for (int half = 0; half < 2; ++half) {
                    const float4* src = (const float4*)(h + off + half * 16);
                    unsigned short tmp[16];
#pragma unroll
                    for (int j = 0; j < 4; ++j) {
                        float4 v = src[j];
                        tmp[j*4+0]=f2bf(v.x); tmp[j*4+1]=f2bf(v.y);
                        tmp[j*4+2]=f2bf(v.z); tmp[j*4+3]=f2bf(v.w);
                    }
                    *(u16x8*)(hb + off + half * 16)     = *(const u16x8*)&tmp[0];
                    *(u16x8*)(hb + off + half * 16 + 8) = *(const u16x8*)&tmp[8];
                }
            }
        }
    }
    grid.sync();

    const int l = t & 63;
    const int w = __builtin_amdgcn_readfirstlane(t >> 6);
    const int r16 = l & 15, kb = l >> 4;
    const int row = t >> 2, q = t & 3;
    unsigned short* Wsh = (unsigned short*)smem;
    unsigned short* Hs  = ((unsigned short*)smem) + DIM * KPAD;

    // ---- P2: bucket + self GEMM (independent; both need only P1) ----
    for (int task = bid; task < P2_TASKS; task += GB) {
        if (task < T_BK) {
            int n = task * 256 + t;
            if (n < N_NODES) {
                int li = ws[OFF_LAST + n];
                if (li >= 0) {
                    int r = edges[li * 3 + 1];
                    int s = edges[li * 3 + 0];
                    int pos = atomicAdd(&ws[OFF_CUR + r], 1);
                    if (pos < CAP) {
                        ws[OFF_BN + r * CAP + pos] = n;
                        ws[OFF_BS + r * CAP + pos] = s;
                    }
                }
            }
        } else {
            int base = (task - T_BK) * 64;
            __syncthreads();
            {
                const unsigned short* wsrc = wt + (size_t)NUM_RELS * DIM * DIM + row * DIM + q * 16;
                *(u16x8*)&Wsh[row * KPAD + q * 16]     = *(const u16x8*)wsrc;
                *(u16x8*)&Wsh[row * KPAD + q * 16 + 8] = *(const u16x8*)(wsrc + 8);
                int n = base + row; if (n >= N_NODES) n = N_NODES - 1;
                const unsigned short* hsrc = hb + (size_t)n * DIM + q * 16;
                *(u16x8*)&Hs[row * KPAD + q * 16]     = *(const u16x8*)hsrc;
                *(u16x8*)&Hs[row * KPAD + q * 16 + 8] = *(const u16x8*)(hsrc + 8);
            }
            __syncthreads();
            bf16x8 a0 = *(const bf16x8*)&Hs[(w * 16 + r16) * KPAD + kb * 8];
            bf16x8 a1 = *(const bf16x8*)&Hs[(w * 16 + r16) * KPAD + 32 + kb * 8];
#pragma unroll
            for (int n4 = 0; n4 < 4; ++n4) {
                bf16x8 b0 = *(const bf16x8*)&Wsh[(n4 * 16 + r16) * KPAD + kb * 8];
                bf16x8 b1 = *(const bf16x8*)&Wsh[(n4 * 16 + r16) * KPAD + 32 + kb * 8];
                f32x4 acc = {0.f, 0.f, 0.f, 0.f};
                acc = __builtin_amdgcn_mfma_f32_16x16x32_bf16(a0, b0, acc, 0, 0, 0);
                acc = __builtin_amdgcn_mfma_f32_16x16x32_bf16(a1, b1, acc, 0, 0, 0);
#pragma unroll
                for (int r = 0; r < 4; ++r) {
                    int nn = base + w * 16 + kb * 4 + r;     // C row = (l>>4)*4 + r
                    if (nn < N_NODES) out[(size_t)nn * DIM + n4 * 16 + r16] = acc[r];
                }
            }
        }
    }
    grid.sync();

    // ---- P3: msg GEMM: out[n] += h[src] @ W[rel] ----
    for (int task = bid; task < MSG_TASKS; task += GB) {
        __syncthreads();                          // LDS reuse guard (block-uniform path)
        int rel = task >> 3, tile = task & 7;
        int c = ws[OFF_CUR + rel];
        if (c > CAP) c = CAP;
        int start = tile * 64;
        if (start >= c) continue;

        const int* bn = ws + OFF_BN + rel * CAP;
        const int* bs = ws + OFF_BS + rel * CAP;
        {
            const unsigned short* wsrc = wt + (size_t)rel * DIM * DIM + row * DIM + q * 16;
            *(u16x8*)&Wsh[row * KPAD + q * 16]     = *(const u16x8*)wsrc;
            *(u16x8*)&Wsh[row * KPAD + q * 16 + 8] = *(const u16x8*)(wsrc + 8);
            int pos = start + row; if (pos >= c) pos = c - 1;
            int s = bs[pos];
            const unsigned short* hsrc = hb + (size_t)s * DIM + q * 16;
            *(u16x8*)&Hs[row * KPAD + q * 16]     = *(const u16x8*)hsrc;
            *(u16x8*)&Hs[row * KPAD + q * 16 + 8] = *(const u16x8*)(hsrc + 8);
        }
        __syncthreads();
        bf16x8 a0 = *(const bf16x8*)&Hs[(w * 16 + r16) * KPAD + kb * 8];
        bf16x8 a1 = *(const bf16x8*)&Hs[(w * 16 + r16) * KPAD + 32 + kb * 8];
        int nn[4]; bool vv[4];
#pragma unroll
        for (int r = 0; r < 4; ++r) {
            int p = start + w * 16 + kb * 4 + r;
            vv[r] = p < c;
            nn[r] = bn[vv[r] ? p : 0];
        }
#pragma unroll
        for (int n4 = 0; n4 < 4; ++n4) {
            bf16x8 b0 = *(const bf16x8*)&Wsh[(n4 * 16 + r16) * KPAD + kb * 8];
            bf16x8 b1 = *(const bf16x8*)&Wsh[(n4 * 16 + r16) * KPAD + 32 + kb * 8];
            f32x4 acc = {0.f, 0.f, 0.f, 0.f};
            acc = __builtin_amdgcn_mfma_f32_16x16x32_bf16(a0, b0, acc, 0, 0, 0);
            acc = __builtin_amdgcn_mfma_f32_16x16x32_bf16(a1, b1, acc, 0, 0, 0);
#pragma unroll
            for (int r = 0; r < 4; ++r)
                if (vv[r]) out[(size_t)nn[r] * DIM + n4 * 16 + r16] += acc[r];
        }
    }
}

extern "C" void kernel_launch(void* const* d_in, const int* in_sizes, int n_in,
                              void* d_out, int out_size, void* d_ws, size_t ws_size,
                              hipStream_t stream) {
    const float* h      = (const float*)d_in[0];
    const int*   edges  = (const int*)d_in[1];
    const float* weight = (const float*)d_in[2];
    const float* wself  = (const float*)d_in[3];
    float* out = (float*)d_out;
    int* wsi = (int*)d_ws;
    unsigned short* hb = (unsigned short*)((char*)d_ws + HB_OFF);
    unsigned short* wt = (unsigned short*)((char*)d_ws + WT_OFF);

    void* args[] = {(void*)&h, (void*)&edges, (void*)&weight, (void*)&wself,
                    (void*)&wsi, (void*)&hb, (void*)&wt, (void*)&out};
    hipLaunchCooperativeKernel((const void*)fused_kernel, dim3(GB), dim3(256),
                               args, 0, stream);
}

// Round 13
// 68.643 us; speedup vs baseline: 4.2562x; 4.2562x over previous
//
#include <hip/hip_runtime.h>

#define N_NODES 50000
#define N_EDGES 100000
#define NUM_RELS 200
#define DIM 64
#define CAP 512
#define TILES 8
#define KPAD 72            // padded K-stride (ushorts); 144B rows, 16B aligned
#define NE_CAP 8192        // no-in-edge list capacity (expected ~6767)

typedef __attribute__((ext_vector_type(8))) short bf16x8;
typedef __attribute__((ext_vector_type(8))) unsigned short u16x8;
typedef __attribute__((ext_vector_type(4))) float f32x4;

// ---- workspace layout ----
// int32 region:
#define OFF_LAST 0               // 50000
#define OFF_CUR  50000           // 201 counters (rel 0..199, no-edge at 200)
#define OFF_BN   50208           // 200*512
#define OFF_BS   152608
#define OFF_NE   255008          // NE_CAP
// byte offsets (16B aligned):
#define HB_OFF   1052800u        // bf16 h: 50000*64 ushorts
#define WT_OFF   7452800u        // bf16 W^T (K-major): 201*64*64 (wself = idx 200)

__device__ __forceinline__ unsigned short f2bf(float x) {
    union { float f; unsigned u; } v; v.f = x;
    unsigned r = v.u + 0x7FFFu + ((v.u >> 16) & 1u);   // RNE
    return (unsigned short)(r >> 16);
}

// ---------- K1: edge_max + W transpose/convert + h convert ----------
#define T_EM 391                 // ceil(100000/256)
#define T_WT 201
#define T_HC 391                 // 8192 floats per task

__global__ __launch_bounds__(256) void prep_kernel(
    const float* __restrict__ h, const float* __restrict__ weight,
    const float* __restrict__ wself, const int* __restrict__ edges,
    int* __restrict__ ws, unsigned short* __restrict__ hb,
    unsigned short* __restrict__ wt)
{
    __shared__ float Wl[DIM * DIM];
    int b = blockIdx.x, t = threadIdx.x;

    if (b < T_EM) {
        int e = b * 256 + t;
        if (e < N_EDGES) atomicMax(&ws[OFF_LAST + edges[e * 3 + 2]], e);
        return;
    }
    if (b < T_EM + T_WT) {
        int rel = b - T_EM;
        const float* src = (rel < NUM_RELS) ? (weight + (size_t)rel * DIM * DIM) : wself;
#pragma unroll
        for (int j = 0; j < 16; ++j) Wl[t + j * 256] = src[t + j * 256];
        __syncthreads();
        int cc = t >> 2, q = t & 3;
        unsigned short tmp[16];
#pragma unroll
        for (int kk = 0; kk < 16; ++kk) tmp[kk] = f2bf(Wl[(q * 16 + kk) * DIM + cc]);
        unsigned short* dst = wt + (size_t)rel * DIM * DIM + cc * DIM + q * 16;
        *(u16x8*)dst       = *(const u16x8*)&tmp[0];
        *(u16x8*)(dst + 8) = *(const u16x8*)&tmp[8];
        return;
    }
    {
        long off = (long)(b - T_EM - T_WT) * 8192 + (long)t * 32;
        if (off < (long)N_NODES * DIM) {
#pragma unroll
            for (int half = 0; half < 2; ++half) {
                const float4* src = (const float4*)(h + off + half * 16);
                unsigned short tmp[16];
#pragma unroll
                for (int j = 0; j < 4; ++j) {
                    float4 v = src[j];
                    tmp[j*4+0]=f2bf(v.x); tmp[j*4+1]=f2bf(v.y);
                    tmp[j*4+2]=f2bf(v.z); tmp[j*4+3]=f2bf(v.w);
                }
                *(u16x8*)(hb + off + half * 16)     = *(const u16x8*)&tmp[0];
                *(u16x8*)(hb + off + half * 16 + 8) = *(const u16x8*)&tmp[8];
            }
        }
    }
}

// ---------- K2: bucket nodes by rel-of-last-edge; no-edge nodes to NE list ----------
__global__ __launch_bounds__(256) void bucket_kernel(const int* __restrict__ edges,
                                                     int* __restrict__ ws) {
    int n = blockIdx.x * 256 + threadIdx.x;
    if (n >= N_NODES) return;
    int li = ws[OFF_LAST + n];
    if (li >= 0) {
        int r = edges[li * 3 + 1];
        int s = edges[li * 3 + 0];
        int pos = atomicAdd(&ws[OFF_CUR + r], 1);
        if (pos < CAP) {
            ws[OFF_BN + r * CAP + pos] = n;
            ws[OFF_BS + r * CAP + pos] = s;
        }
    } else {
        int pos = atomicAdd(&ws[OFF_CUR + NUM_RELS], 1);
        if (pos < NE_CAP) ws[OFF_NE + pos] = n;
    }
}

// ---------- K3: all GEMMs, no ordering hazard ----------
// rel tiles: out[n] = h[n]@Wself + h[src]@Wrel   (mfma chain, '=' store)
// NE tiles : out[n] = h[n]@Wself
#define REL_BLKS (NUM_RELS * TILES)   // 1600
#define NE_BLKS  (NE_CAP / 64)        // 128

__global__ __launch_bounds__(256) void gemm_kernel(
    const unsigned short* __restrict__ hb, const unsigned short* __restrict__ wt,
    const int* __restrict__ ws, float* __restrict__ out)
{
    __shared__ unsigned short Wr[DIM * KPAD];   // W_rel^T
    __shared__ unsigned short Wf[DIM * KPAD];   // W_self^T
    __shared__ unsigned short Hs[DIM * KPAD];   // src rows
    __shared__ unsigned short Hn[DIM * KPAD];   // own rows

    int t = threadIdx.x;
    int l = t & 63;
    int w = __builtin_amdgcn_readfirstlane(t >> 6);
    int r16 = l & 15, kb = l >> 4;
    int row = t >> 2, q = t & 3;
    const unsigned short* wts = wt + (size_t)NUM_RELS * DIM * DIM;

    if (blockIdx.x < REL_BLKS) {
        int rel = blockIdx.x >> 3, tile = blockIdx.x & 7;
        int c = ws[OFF_CUR + rel];
        if (c > CAP) c = CAP;
        int start = tile * 64;
        if (start >= c) return;

        const int* bn = ws + OFF_BN + rel * CAP;
        const int* bs = ws + OFF_BS + rel * CAP;
        {
            const unsigned short* wsrc = wt + (size_t)rel * DIM * DIM + row * DIM + q * 16;
            *(u16x8*)&Wr[row * KPAD + q * 16]     = *(const u16x8*)wsrc;
            *(u16x8*)&Wr[row * KPAD + q * 16 + 8] = *(const u16x8*)(wsrc + 8);
            const unsigned short* fsrc = wts + row * DIM + q * 16;
            *(u16x8*)&Wf[row * KPAD + q * 16]     = *(const u16x8*)fsrc;
            *(u16x8*)&Wf[row * KPAD + q * 16 + 8] = *(const u16x8*)(fsrc + 8);
            int pos = start + row; if (pos >= c) pos = c - 1;
            int s = bs[pos], n = bn[pos];
            const unsigned short* hsrc = hb + (size_t)s * DIM + q * 16;
            *(u16x8*)&Hs[row * KPAD + q * 16]     = *(const u16x8*)hsrc;
            *(u16x8*)&Hs[row * KPAD + q * 16 + 8] = *(const u16x8*)(hsrc + 8);
            const unsigned short* hn = hb + (size_t)n * DIM + q * 16;
            *(u16x8*)&Hn[row * KPAD + q * 16]     = *(const u16x8*)hn;
            *(u16x8*)&Hn[row * KPAD + q * 16 + 8] = *(const u16x8*)(hn + 8);
        }
        __syncthreads();

        bf16x8 as0 = *(const bf16x8*)&Hs[(w * 16 + r16) * KPAD + kb * 8];
        bf16x8 as1 = *(const bf16x8*)&Hs[(w * 16 + r16) * KPAD + 32 + kb * 8];
        bf16x8 an0 = *(const bf16x8*)&Hn[(w * 16 + r16) * KPAD + kb * 8];
        bf16x8 an1 = *(const bf16x8*)&Hn[(w * 16 + r16) * KPAD + 32 + kb * 8];

        int nn[4]; bool vv[4];
#pragma unroll
        for (int r = 0; r < 4; ++r) {
            int p = start + w * 16 + kb * 4 + r;     // C row = (l>>4)*4 + r
            vv[r] = p < c;
            nn[r] = bn[vv[r] ? p : 0];
        }
#pragma unroll
        for (int n4 = 0; n4 < 4; ++n4) {
            bf16x8 br0 = *(const bf16x8*)&Wr[(n4 * 16 + r16) * KPAD + kb * 8];
            bf16x8 br1 = *(const bf16x8*)&Wr[(n4 * 16 + r16) * KPAD + 32 + kb * 8];
            bf16x8 bf0 = *(const bf16x8*)&Wf[(n4 * 16 + r16) * KPAD + kb * 8];
            bf16x8 bf1 = *(const bf16x8*)&Wf[(n4 * 16 + r16) * KPAD + 32 + kb * 8];
            f32x4 acc = {0.f, 0.f, 0.f, 0.f};
            acc = __builtin_amdgcn_mfma_f32_16x16x32_bf16(as0, br0, acc, 0, 0, 0);
            acc = __builtin_amdgcn_mfma_f32_16x16x32_bf16(as1, br1, acc, 0, 0, 0);
            acc = __builtin_amdgcn_mfma_f32_16x16x32_bf16(an0, bf0, acc, 0, 0, 0);
            acc = __builtin_amdgcn_mfma_f32_16x16x32_bf16(an1, bf1, acc, 0, 0, 0);
#pragma unroll
            for (int r = 0; r < 4; ++r)
                if (vv[r]) out[(size_t)nn[r] * DIM + n4 * 16 + r16] = acc[r];
        }
    } else {
        int idx = blockIdx.x - REL_BLKS;
        int cnt = ws[OFF_CUR + NUM_RELS];
        if (cnt > NE_CAP) cnt = NE_CAP;
        int start = idx * 64;
        if (start >= cnt) return;

        const int* ne = ws + OFF_NE;
        {
            const unsigned short* fsrc = wts + row * DIM + q * 16;
            *(u16x8*)&Wf[row * KPAD + q * 16]     = *(const u16x8*)fsrc;
            *(u16x8*)&Wf[row * KPAD + q * 16 + 8] = *(const u16x8*)(fsrc + 8);
            int pos = start + row; if (pos >= cnt) pos = cnt - 1;
            int n = ne[pos];
            const unsigned short* hn = hb + (size_t)n * DIM + q * 16;
            *(u16x8*)&Hn[row * KPAD + q * 16]     = *(const u16x8*)hn;
            *(u16x8*)&Hn[row * KPAD + q * 16 + 8] = *(const u16x8*)(hn + 8);
        }
        __syncthreads();

        bf16x8 an0 = *(const bf16x8*)&Hn[(w * 16 + r16) * KPAD + kb * 8];
        bf16x8 an1 = *(const bf16x8*)&Hn[(w * 16 + r16) * KPAD + 32 + kb * 8];

        int nn[4]; bool vv[4];
#pragma unroll
        for (int r = 0; r < 4; ++r) {
            int p = start + w * 16 + kb * 4 + r;
            vv[r] = p < cnt;
            nn[r] = ne[vv[r] ? p : 0];
        }
#pragma unroll
        for (int n4 = 0; n4 < 4; ++n4) {
            bf16x8 bf0 = *(const bf16x8*)&Wf[(n4 * 16 + r16) * KPAD + kb * 8];
            bf16x8 bf1 = *(const bf16x8*)&Wf[(n4 * 16 + r16) * KPAD + 32 + kb * 8];
            f32x4 acc = {0.f, 0.f, 0.f, 0.f};
            acc = __builtin_amdgcn_mfma_f32_16x16x32_bf16(an0, bf0, acc, 0, 0, 0);
            acc = __builtin_amdgcn_mfma_f32_16x16x32_bf16(an1, bf1, acc, 0, 0, 0);
#pragma unroll
            for (int r = 0; r < 4; ++r)
                if (vv[r]) out[(size_t)nn[r] * DIM + n4 * 16 + r16] = acc[r];
        }
    }
}

extern "C" void kernel_launch(void* const* d_in, const int* in_sizes, int n_in,
                              void* d_out, int out_size, void* d_ws, size_t ws_size,
                              hipStream_t stream) {
    const float* h      = (const float*)d_in[0];
    const int*   edges  = (const int*)d_in[1];
    const float* weight = (const float*)d_in[2];
    const float* wself  = (const float*)d_in[3];
    float* out = (float*)d_out;
    int* wsi = (int*)d_ws;
    unsigned short* hb = (unsigned short*)((char*)d_ws + HB_OFF);
    unsigned short* wt = (unsigned short*)((char*)d_ws + WT_OFF);

    hipMemsetAsync((char*)d_ws + (size_t)OFF_LAST * 4, 0xFF, (size_t)N_NODES * 4, stream); // last=-1
    hipMemsetAsync((char*)d_ws + (size_t)OFF_CUR * 4, 0, 208 * 4, stream);                 // counters=0

    prep_kernel<<<T_EM + T_WT + T_HC, 256, 0, stream>>>(h, weight, wself, edges, wsi, hb, wt);
    bucket_kernel<<<(N_NODES + 255) / 256, 256, 0, stream>>>(edges, wsi);
    gemm_kernel<<<REL_BLKS + NE_BLKS, 256, 0, stream>>>(hb, wt, wsi, out);
}

// Round 14
// 67.042 us; speedup vs baseline: 4.3579x; 1.0239x over previous
//
#include <hip/hip_runtime.h>

#define N_NODES 50000
#define N_EDGES 100000
#define NUM_RELS 200
#define DIM 64
#define CAP 512
#define TILES 8
#define KPAD 72            // padded K-stride (ushorts); 144B rows, 16B aligned

typedef __attribute__((ext_vector_type(8))) short bf16x8;
typedef __attribute__((ext_vector_type(8))) unsigned short u16x8;
typedef __attribute__((ext_vector_type(4))) float f32x4;

// ---- workspace layout (int32 elements) ----
// last[50000] ++ cur[201] ++ pad ++ bn[200*512] ++ bs[200*512]
#define OFF_LAST 0
#define OFF_CUR  50000           // raw counters, init 0xFF (=-1); logical = raw+1
#define OFF_BN   50208
#define OFF_BS   152608

__device__ __forceinline__ unsigned short f2bf(float x) {
    union { float f; unsigned u; } v; v.f = x;
    unsigned r = v.u + 0x7FFFu + ((v.u >> 16) & 1u);   // RNE
    return (unsigned short)(r >> 16);
}

// Stage fp32 row-major 64x64 W into LDS as bf16 [out-col][k] (KPAD stride).
__device__ __forceinline__ void stage_w_t(const float* __restrict__ W,
                                          unsigned short* __restrict__ Wsh, int t) {
    int c = t >> 2, q = t & 3;
    unsigned short tmp[16];
#pragma unroll
    for (int kk = 0; kk < 16; ++kk)
        tmp[kk] = f2bf(W[(q * 16 + kk) * DIM + c]);
    *(u16x8*)&Wsh[c * KPAD + q * 16]     = *(const u16x8*)&tmp[0];
    *(u16x8*)&Wsh[c * KPAD + q * 16 + 8] = *(const u16x8*)&tmp[8];
}

// Stage one fp32 h row quarter into Hs[row][q*16..] as bf16.
__device__ __forceinline__ void stage_h_row(const float* __restrict__ hrow,
                                            unsigned short* __restrict__ Hs,
                                            int row, int q) {
    const float4* src = (const float4*)(hrow + q * 16);
    unsigned short tmp[16];
#pragma unroll
    for (int j = 0; j < 4; ++j) {
        float4 v = src[j];
        tmp[j*4+0] = f2bf(v.x); tmp[j*4+1] = f2bf(v.y);
        tmp[j*4+2] = f2bf(v.z); tmp[j*4+3] = f2bf(v.w);
    }
    *(u16x8*)&Hs[row * KPAD + q * 16]     = *(const u16x8*)&tmp[0];
    *(u16x8*)&Hs[row * KPAD + q * 16 + 8] = *(const u16x8*)&tmp[8];
}

// ---------- K1: edge_max + self GEMM (independent halves) ----------
#define T_EM 391                 // ceil(100000/256)
#define NODE_TILES 782           // ceil(50000/64)

__global__ __launch_bounds__(256) void edge_self_kernel(
    const float* __restrict__ h, const int* __restrict__ edges,
    const float* __restrict__ wself, int* __restrict__ ws,
    float* __restrict__ out)
{
    __shared__ unsigned short Wsh[DIM * KPAD];
    __shared__ unsigned short Hs[DIM * KPAD];
    int t = threadIdx.x;

    if (blockIdx.x < T_EM) {
        int e = blockIdx.x * 256 + t;
        if (e < N_EDGES) atomicMax(&ws[OFF_LAST + edges[e * 3 + 2]], e);
        return;
    }

    int base = (blockIdx.x - T_EM) * 64;
    {
        stage_w_t(wself, Wsh, t);
        int row = t >> 2, q = t & 3;
        int n = base + row; if (n >= N_NODES) n = N_NODES - 1;
        stage_h_row(h + (size_t)n * DIM, Hs, row, q);
    }
    __syncthreads();

    int l = t & 63;
    int w = __builtin_amdgcn_readfirstlane(t >> 6);
    int r16 = l & 15, kb = l >> 4;

    bf16x8 a0 = *(const bf16x8*)&Hs[(w * 16 + r16) * KPAD + kb * 8];
    bf16x8 a1 = *(const bf16x8*)&Hs[(w * 16 + r16) * KPAD + 32 + kb * 8];

#pragma unroll
    for (int n4 = 0; n4 < 4; ++n4) {
        bf16x8 b0 = *(const bf16x8*)&Wsh[(n4 * 16 + r16) * KPAD + kb * 8];
        bf16x8 b1 = *(const bf16x8*)&Wsh[(n4 * 16 + r16) * KPAD + 32 + kb * 8];
        f32x4 acc = {0.f, 0.f, 0.f, 0.f};
        acc = __builtin_amdgcn_mfma_f32_16x16x32_bf16(a0, b0, acc, 0, 0, 0);
        acc = __builtin_amdgcn_mfma_f32_16x16x32_bf16(a1, b1, acc, 0, 0, 0);
#pragma unroll
        for (int r = 0; r < 4; ++r) {
            int nn = base + w * 16 + kb * 4 + r;       // C row = (l>>4)*4 + r
            if (nn < N_NODES) out[(size_t)nn * DIM + n4 * 16 + r16] = acc[r];
        }
    }
}

// ---------- K2: bucket nodes by rel of last incoming edge ----------
__global__ __launch_bounds__(256) void bucket_kernel(const int* __restrict__ edges,
                                                     int* __restrict__ ws) {
    int n = blockIdx.x * 256 + threadIdx.x;
    if (n >= N_NODES) return;
    int li = ws[OFF_LAST + n];
    if (li < 0) return;                        // no in-edge: self already written
    int r = edges[li * 3 + 1];
    int s = edges[li * 3 + 0];
    int pos = atomicAdd(&ws[OFF_CUR + r], 1) + 1;   // raw starts at -1
    if (pos < CAP) {
        ws[OFF_BN + r * CAP + pos] = n;
        ws[OFF_BS + r * CAP + pos] = s;
    }
}

// ---------- K3: msg GEMM: out[n] += h[src] @ W[rel] ----------
__global__ __launch_bounds__(256) void msg_kernel(
    const float* __restrict__ h, const float* __restrict__ weight,
    const int* __restrict__ ws, float* __restrict__ out)
{
    __shared__ unsigned short Wsh[DIM * KPAD];
    __shared__ unsigned short Hs[DIM * KPAD];

    int rel = blockIdx.x >> 3, tile = blockIdx.x & 7;
    int c = ws[OFF_CUR + rel] + 1;             // logical count
    if (c > CAP) c = CAP;
    int start = tile * 64;
    if (start >= c) return;

    int t = threadIdx.x;
    const int* bn = ws + OFF_BN + rel * CAP;
    const int* bs = ws + OFF_BS + rel * CAP;

    {
        stage_w_t(weight + (size_t)rel * DIM * DIM, Wsh, t);
        int row = t >> 2, q = t & 3;
        int pos = start + row; if (pos >= c) pos = c - 1;
        int s = bs[pos];
        stage_h_row(h + (size_t)s * DIM, Hs, row, q);
    }
    __syncthreads();

    int l = t & 63;
    int w = __builtin_amdgcn_readfirstlane(t >> 6);
    int r16 = l & 15, kb = l >> 4;

    bf16x8 a0 = *(const bf16x8*)&Hs[(w * 16 + r16) * KPAD + kb * 8];
    bf16x8 a1 = *(const bf16x8*)&Hs[(w * 16 + r16) * KPAD + 32 + kb * 8];

    int nn[4]; bool vv[4];
#pragma unroll
    for (int r = 0; r < 4; ++r) {
        int p = start + w * 16 + kb * 4 + r;
        vv[r] = p < c;
        nn[r] = bn[vv[r] ? p : 0];
    }

#pragma unroll
    for (int n4 = 0; n4 < 4; ++n4) {
        bf16x8 b0 = *(const bf16x8*)&Wsh[(n4 * 16 + r16) * KPAD + kb * 8];
        bf16x8 b1 = *(const bf16x8*)&Wsh[(n4 * 16 + r16) * KPAD + 32 + kb * 8];
        f32x4 acc = {0.f, 0.f, 0.f, 0.f};
        acc = __builtin_amdgcn_mfma_f32_16x16x32_bf16(a0, b0, acc, 0, 0, 0);
        acc = __builtin_amdgcn_mfma_f32_16x16x32_bf16(a1, b1, acc, 0, 0, 0);
#pragma unroll
        for (int r = 0; r < 4; ++r)
            if (vv[r]) out[(size_t)nn[r] * DIM + n4 * 16 + r16] += acc[r];
    }
}

extern "C" void kernel_launch(void* const* d_in, const int* in_sizes, int n_in,
                              void* d_out, int out_size, void* d_ws, size_t ws_size,
                              hipStream_t stream) {
    const float* h      = (const float*)d_in[0];
    const int*   edges  = (const int*)d_in[1];
    const float* weight = (const float*)d_in[2];
    const float* wself  = (const float*)d_in[3];
    float* out = (float*)d_out;
    int* ws = (int*)d_ws;

    // one fill: last = -1 AND cur_raw = -1 (logical count = raw+1)
    hipMemsetAsync(d_ws, 0xFF, (size_t)(N_NODES + 208) * 4, stream);

    edge_self_kernel<<<T_EM + NODE_TILES, 256, 0, stream>>>(h, edges, wself, ws, out);
    bucket_kernel<<<(N_NODES + 255) / 256, 256, 0, stream>>>(edges, ws);
    msg_kernel<<<NUM_RELS * TILES, 256, 0, stream>>>(h, weight, ws, out);
}

// Round 15
// 62.764 us; speedup vs baseline: 4.6549x; 1.0682x over previous
//
#include <hip/hip_runtime.h>

#define N_NODES 50000
#define N_EDGES 100000
#define NUM_RELS 200
#define DIM 64
#define CAP 512
#define TILES 8
#define KPAD 72            // padded K-stride in ushorts (144B): balanced banks, 16B aligned

typedef __attribute__((ext_vector_type(8))) short bf16x8;
typedef __attribute__((ext_vector_type(8))) unsigned short u16x8;
typedef __attribute__((ext_vector_type(4))) float f32x4;

// ---- workspace layout ----
// int32 region: last[50000] ++ cur[208] ++ bn[200*512] ++ bs[200*512]
#define OFF_LAST 0
#define OFF_CUR  50000           // raw counters, init -1 by 0xFF fill; logical = raw+1
#define OFF_BN   50208
#define OFF_BS   152608
// byte offsets (16B aligned):
#define HB_OFF   1020032u        // bf16 h: 50000*64 ushorts = 6.4 MB
#define WT_OFF   7420032u        // bf16 W^T (K-major): 201*64*64 ushorts (wself = idx 200)

__device__ __forceinline__ unsigned short f2bf(float x) {
    union { float f; unsigned u; } v; v.f = x;
    unsigned r = v.u + 0x7FFFu + ((v.u >> 16) & 1u);   // RNE
    return (unsigned short)(r >> 16);
}

// ---------- K1: edge_max + W transpose/convert + h convert (init via memset) ----------
#define T_EM 391                 // ceil(100000/256)
#define T_WT 201                 // 200 rels + wself
#define T_HC 391                 // 8192 floats per task

__global__ __launch_bounds__(256) void prep_kernel(
    const float* __restrict__ h, const float* __restrict__ weight,
    const float* __restrict__ wself, const int* __restrict__ edges,
    int* __restrict__ ws, unsigned short* __restrict__ hb,
    unsigned short* __restrict__ wt)
{
    __shared__ float Wl[DIM * DIM];
    int b = blockIdx.x, t = threadIdx.x;

    if (b < T_EM) {
        int e = b * 256 + t;
        if (e < N_EDGES) atomicMax(&ws[OFF_LAST + edges[e * 3 + 2]], e);
        return;
    }
    if (b < T_EM + T_WT) {
        int rel = b - T_EM;
        const float* src = (rel < NUM_RELS) ? (weight + (size_t)rel * DIM * DIM) : wself;
#pragma unroll
        for (int j = 0; j < 16; ++j) Wl[t + j * 256] = src[t + j * 256];
        __syncthreads();
        int cc = t >> 2, q = t & 3;          // out-col, k-quarter
        unsigned short tmp[16];
#pragma unroll
        for (int kk = 0; kk < 16; ++kk)
            tmp[kk] = f2bf(Wl[(q * 16 + kk) * DIM + cc]);
        unsigned short* dst = wt + (size_t)rel * DIM * DIM + cc * DIM + q * 16;
        *(u16x8*)dst       = *(const u16x8*)&tmp[0];
        *(u16x8*)(dst + 8) = *(const u16x8*)&tmp[8];
        return;
    }
    {
        long off = (long)(b - T_EM - T_WT) * 8192 + (long)t * 32;
        if (off < (long)N_NODES * DIM) {
#pragma unroll
            for (int half = 0; half < 2; ++half) {
                const float4* src = (const float4*)(h + off + half * 16);
                unsigned short tmp[16];
#pragma unroll
                for (int j = 0; j < 4; ++j) {
                    float4 v = src[j];
                    tmp[j*4+0]=f2bf(v.x); tmp[j*4+1]=f2bf(v.y);
                    tmp[j*4+2]=f2bf(v.z); tmp[j*4+3]=f2bf(v.w);
                }
                *(u16x8*)(hb + off + half * 16)     = *(const u16x8*)&tmp[0];
                *(u16x8*)(hb + off + half * 16 + 8) = *(const u16x8*)&tmp[8];
            }
        }
    }
}

// ---------- K2: bucket + self GEMM (both depend only on K1) ----------
#define BK_BLKS 196              // ceil(50000/256)
#define NODE_TILES 782           // ceil(50000/64)

__global__ __launch_bounds__(256) void bucket_self_kernel(
    const int* __restrict__ edges, const unsigned short* __restrict__ hb,
    const unsigned short* __restrict__ wt, int* __restrict__ ws,
    float* __restrict__ out)
{
    __shared__ unsigned short Wsh[DIM * KPAD];
    __shared__ unsigned short Hs[DIM * KPAD];
    int t = threadIdx.x;

    if (blockIdx.x < BK_BLKS) {
        int n = blockIdx.x * 256 + t;
        if (n < N_NODES) {
            int li = ws[OFF_LAST + n];
            if (li >= 0) {
                int r = edges[li * 3 + 1];
                int s = edges[li * 3 + 0];
                int pos = atomicAdd(&ws[OFF_CUR + r], 1) + 1;   // raw starts at -1
                if (pos < CAP) {
                    ws[OFF_BN + r * CAP + pos] = n;
                    ws[OFF_BS + r * CAP + pos] = s;
                }
            }
        }
        return;
    }

    int base = (blockIdx.x - BK_BLKS) * 64;
    int row = t >> 2, q = t & 3;
    {
        const unsigned short* wsrc = wt + (size_t)NUM_RELS * DIM * DIM + row * DIM + q * 16;
        *(u16x8*)&Wsh[row * KPAD + q * 16]     = *(const u16x8*)wsrc;
        *(u16x8*)&Wsh[row * KPAD + q * 16 + 8] = *(const u16x8*)(wsrc + 8);
        int n = base + row; if (n >= N_NODES) n = N_NODES - 1;
        const unsigned short* hsrc = hb + (size_t)n * DIM + q * 16;
        *(u16x8*)&Hs[row * KPAD + q * 16]     = *(const u16x8*)hsrc;
        *(u16x8*)&Hs[row * KPAD + q * 16 + 8] = *(const u16x8*)(hsrc + 8);
    }
    __syncthreads();

    int l = t & 63;
    int w = __builtin_amdgcn_readfirstlane(t >> 6);   // wave -> 16-row strip
    int r16 = l & 15, kb = l >> 4;

    bf16x8 a0 = *reinterpret_cast<const bf16x8*>(&Hs[(w * 16 + r16) * KPAD + kb * 8]);
    bf16x8 a1 = *reinterpret_cast<const bf16x8*>(&Hs[(w * 16 + r16) * KPAD + 32 + kb * 8]);

    int nn[4]; bool vv[4];
#pragma unroll
    for (int r = 0; r < 4; ++r) {
        nn[r] = base + w * 16 + kb * 4 + r;           // C row = (l>>4)*4 + r
        vv[r] = nn[r] < N_NODES;
    }

#pragma unroll
    for (int n4 = 0; n4 < 4; ++n4) {
        bf16x8 b0 = *reinterpret_cast<const bf16x8*>(&Wsh[(n4 * 16 + r16) * KPAD + kb * 8]);
        bf16x8 b1 = *reinterpret_cast<const bf16x8*>(&Wsh[(n4 * 16 + r16) * KPAD + 32 + kb * 8]);
        f32x4 acc = {0.f, 0.f, 0.f, 0.f};
        acc = __builtin_amdgcn_mfma_f32_16x16x32_bf16(a0, b0, acc, 0, 0, 0);
        acc = __builtin_amdgcn_mfma_f32_16x16x32_bf16(a1, b1, acc, 0, 0, 0);
#pragma unroll
        for (int r = 0; r < 4; ++r)
            if (vv[r]) out[(size_t)nn[r] * DIM + n4 * 16 + r16] = acc[r];
    }
}

// ---------- K3: msg GEMM: out[n] += h[src] @ W[rel] ----------
__global__ __launch_bounds__(256) void msg_kernel(
    const unsigned short* __restrict__ hb, const unsigned short* __restrict__ wt,
    const int* __restrict__ ws, float* __restrict__ out)
{
    __shared__ unsigned short Wsh[DIM * KPAD];
    __shared__ unsigned short Hs[DIM * KPAD];

    int rel = blockIdx.x >> 3;
    int tile = blockIdx.x & 7;
    int c = ws[OFF_CUR + rel] + 1;                    // logical count (raw+1)
    if (c > CAP) c = CAP;
    int start = tile * 64;
    if (start >= c) return;

    int t = threadIdx.x;
    const int* bn = ws + OFF_BN + rel * CAP;
    const int* bs = ws + OFF_BS + rel * CAP;

    int row = t >> 2, q = t & 3;
    {
        const unsigned short* wsrc = wt + (size_t)rel * DIM * DIM + row * DIM + q * 16;
        *(u16x8*)&Wsh[row * KPAD + q * 16]     = *(const u16x8*)wsrc;
        *(u16x8*)&Wsh[row * KPAD + q * 16 + 8] = *(const u16x8*)(wsrc + 8);
        int pos = start + row; if (pos >= c) pos = c - 1;
        int s = bs[pos];
        const unsigned short* hsrc = hb + (size_t)s * DIM + q * 16;
        *(u16x8*)&Hs[row * KPAD + q * 16]     = *(const u16x8*)hsrc;
        *(u16x8*)&Hs[row * KPAD + q * 16 + 8] = *(const u16x8*)(hsrc + 8);
    }
    __syncthreads();

    int l = t & 63;
    int w = __builtin_amdgcn_readfirstlane(t >> 6);
    int r16 = l & 15, kb = l >> 4;

    bf16x8 a0 = *reinterpret_cast<const bf16x8*>(&Hs[(w * 16 + r16) * KPAD + kb * 8]);
    bf16x8 a1 = *reinterpret_cast<const bf16x8*>(&Hs[(w * 16 + r16) * KPAD + 32 + kb * 8]);

    int nn[4]; bool vv[4];
#pragma unroll
    for (int r = 0; r < 4; ++r) {
        int p = start + w * 16 + kb * 4 + r;
        vv[r] = p < c;
        nn[r] = bn[vv[r] ? p : 0];
    }

#pragma unroll
    for (int n4 = 0; n4 < 4; ++n4) {
        bf16x8 b0 = *reinterpret_cast<const bf16x8*>(&Wsh[(n4 * 16 + r16) * KPAD + kb * 8]);
        bf16x8 b1 = *reinterpret_cast<const bf16x8*>(&Wsh[(n4 * 16 + r16) * KPAD + 32 + kb * 8]);
        f32x4 acc = {0.f, 0.f, 0.f, 0.f};
        acc = __builtin_amdgcn_mfma_f32_16x16x32_bf16(a0, b0, acc, 0, 0, 0);
        acc = __builtin_amdgcn_mfma_f32_16x16x32_bf16(a1, b1, acc, 0, 0, 0);
#pragma unroll
        for (int r = 0; r < 4; ++r)
            if (vv[r]) out[(size_t)nn[r] * DIM + n4 * 16 + r16] += acc[r];
    }
}

extern "C" void kernel_launch(void* const* d_in, const int* in_sizes, int n_in,
                              void* d_out, int out_size, void* d_ws, size_t ws_size,
                              hipStream_t stream) {
    const float* h      = (const float*)d_in[0];
    const int*   edges  = (const int*)d_in[1];
    const float* weight = (const float*)d_in[2];
    const float* wself  = (const float*)d_in[3];
    float* out = (float*)d_out;
    int* wsi = (int*)d_ws;
    unsigned short* hb = (unsigned short*)((char*)d_ws + HB_OFF);
    unsigned short* wt = (unsigned short*)((char*)d_ws + WT_OFF);

    // single fill: last = -1 AND raw counters = -1
    hipMemsetAsync(d_ws, 0xFF, (size_t)(N_NODES + 208) * 4, stream);

    prep_kernel<<<T_EM + T_WT + T_HC, 256, 0, stream>>>(h, weight, wself, edges, wsi, hb, wt);
    bucket_self_kernel<<<BK_BLKS + NODE_TILES, 256, 0, stream>>>(edges, hb, wt, wsi, out);
    msg_kernel<<<NUM_RELS * TILES, 256, 0, stream>>>(hb, wt, wsi, out);
}